// Round 3
// baseline (156.555 us; speedup 1.0000x reference)
//
#include <hip/hip_runtime.h>
#include <stdint.h>

typedef unsigned short u16;
typedef __attribute__((ext_vector_type(8))) short short8;
typedef __attribute__((ext_vector_type(4))) short s4v;
typedef __attribute__((ext_vector_type(4))) float floatx4;

#define NB 32
#define NC 256
#define NH 32
#define NW 32
#define NO 256
#define NPIX (NH*NW)     // 1024
#define KPIX 9
#define NG 9             // subarrays (groups)
#define RUN 32           // padded run length (per kernel-tap within group)
#define GK (NG*RUN)      // 288 k-slots per group
#define KTOT (NG*GK)     // 2592 k-slots
#define PADH 34
#define PADSP (PADH*PADH)       // 1156
#define QA_BSTRIDE (PADSP*NC)   // 295936 elems per batch

#define AS1 __attribute__((address_space(1)))
#define AS3 __attribute__((address_space(3)))

// ---------------- fused: per-block absmax slots + zero qa halo borders ----------------
__global__ void fused_pre(const float4* __restrict__ x4, int nx4,
                          const float4* __restrict__ w4, int nw4,
                          float* __restrict__ pmax, u16* __restrict__ qa) {
  int bid = blockIdx.x;
  if (bid >= 1088) {
    int zb = bid - 1088;              // 9 blocks per batch
    int b = zb / 9;
    int rem = (zb % 9) * 256 + threadIdx.x;   // need <2112 (132 px * 16 ch-groups)
    if (rem >= 2112) return;
    int pb = rem >> 4, c16 = rem & 15;
    int y, x;
    if (pb < 68) { y = (pb >= 34) ? 33 : 0; x = pb % 34; }
    else { int q = pb - 68; y = 1 + (q >> 1); x = (q & 1) ? 33 : 0; }
    uint4 z; z.x = z.y = z.z = z.w = 0u;
    *(uint4*)(qa + ((size_t)(b * PADH + y) * PADH + x) * NC + c16 * 16) = z;
    return;
  }
  const float4* p; int n4; int nb, b0;
  if (bid < 1024) { p = x4; n4 = nx4; nb = 1024; b0 = bid; }
  else            { p = w4; n4 = nw4; nb = 64;   b0 = bid - 1024; }
  float m = 0.f;
  for (int i = b0 * blockDim.x + threadIdx.x; i < n4; i += nb * blockDim.x) {
    float4 v = p[i];
    m = fmaxf(m, fmaxf(fmaxf(fabsf(v.x), fabsf(v.y)), fmaxf(fabsf(v.z), fabsf(v.w))));
  }
#pragma unroll
  for (int off = 32; off > 0; off >>= 1)
    m = fmaxf(m, __shfl_down(m, off, 64));
  __shared__ float sm[4];
  int lane = threadIdx.x & 63, wv = threadIdx.x >> 6;
  if (lane == 0) sm[wv] = m;
  __syncthreads();
  if (threadIdx.x == 0)
    pmax[bid] = fmaxf(fmaxf(sm[0], sm[1]), fmaxf(sm[2], sm[3]));
}

// helper: reduce the 1024 x-slots and 64 w-slots
__device__ inline void reduce_pmax(const float* pmax, int tid, int nthreads,
                                   float* sred, float& mx_out, float& mw_out) {
  const float4* pf4 = (const float4*)pmax;
  float mx = 0.f, mw = 0.f;
  for (int t = tid; t < 256; t += nthreads) {
    float4 v = pf4[t];
    mx = fmaxf(mx, fmaxf(fmaxf(v.x, v.y), fmaxf(v.z, v.w)));
  }
  if (tid < 16) {
    float4 v = pf4[256 + tid];
    mw = fmaxf(fmaxf(v.x, v.y), fmaxf(v.z, v.w));
  }
#pragma unroll
  for (int off = 32; off > 0; off >>= 1) {
    mx = fmaxf(mx, __shfl_down(mx, off, 64));
    mw = fmaxf(mw, __shfl_down(mw, off, 64));
  }
  int lane = tid & 63, wv = tid >> 6, nw = nthreads >> 6;
  if (lane == 0) { sred[wv] = mx; sred[8 + wv] = mw; }
  __syncthreads();
  mx = sred[0]; mw = sred[8];
  for (int i = 1; i < nw; i++) { mx = fmaxf(mx, sred[i]); mw = fmaxf(mw, sred[8 + i]); }
  mx_out = mx; mw_out = mw;
}

// ---------------- fused quantization (unchanged, proven) ----------------
__global__ void fused_quant(const float* __restrict__ x, const float* __restrict__ w,
                            const float* __restrict__ pmax,
                            u16* __restrict__ qa, u16* __restrict__ wq,
                            float* __restrict__ lossp) {
  __shared__ float sred[16];
  float mx, mw;
  reduce_pmax(pmax, threadIdx.x, 256, sred, mx, mw);
  int bid = blockIdx.x, tid = threadIdx.x;
  if (bid < 1024) {
    __shared__ u16 ts[32][264];        // [x][c], row stride 264 (16B-aligned rows)
    double s = (double)mx + 1e-12;
    double inv = 255.0 / s;
    int b = bid >> 5, y = bid & 31;
    const float4* x4 = (const float4*)x;
    int xc = tid & 7, crow = tid >> 3;
#pragma unroll
    for (int it = 0; it < 8; it++) {
      int c = crow + 32 * it;
      float4 v = x4[((size_t)(b * NC + c) * NH + y) * 8 + xc];
      float q0 = (float)rint((double)v.x * inv);
      float q1 = (float)rint((double)v.y * inv);
      float q2 = (float)rint((double)v.z * inv);
      float q3 = (float)rint((double)v.w * inv);
      ts[xc * 4 + 0][c] = (u16)(__float_as_uint(q0) >> 16);
      ts[xc * 4 + 1][c] = (u16)(__float_as_uint(q1) >> 16);
      ts[xc * 4 + 2][c] = (u16)(__float_as_uint(q2) >> 16);
      ts[xc * 4 + 3][c] = (u16)(__float_as_uint(q3) >> 16);
    }
    __syncthreads();
    int xx = tid >> 3, qwl = tid & 7;
    u16* orow = qa + ((size_t)(b * PADH + y + 1) * PADH + (xx + 1)) * NC;
#pragma unroll
    for (int it = 0; it < 4; it++) {
      int qw = qwl + 8 * it;
      *(uint4*)(orow + qw * 8) = *(const uint4*)&ts[xx][qw * 8];
    }
    return;
  }
  // ---- weights: 2592 blocks cover NO*KTOT = 663552 slots exactly ----
  double s = (double)mw + 1e-12;
  double inv = 15.0 / s;
  int idx = (bid - 1024) * 256 + tid;
  if (idx == 0) *lossp = 0.0f;                  // a_loss output
  int o = idx / KTOT, kk = idx % KTOT;
  int g = kk / GK, rem = kk % GK;
  int r = rem / RUN, j = rem % RUN;
  int clo = (256 * g - r + 8) / 9;
  int chi = (256 * (g + 1) - r + 8) / 9; if (chi > NC) chi = NC;
  int cst = clo & ~3;
  int c = cst + j;
  float val = 0.f;
  if (c >= clo && c < chi) {
    float wv = w[((size_t)o * NC + c) * KPIX + r];
    val = (float)rint((double)wv * inv);
  }
  wq[idx] = (u16)(__float_as_uint(val) >> 16);
}

// ---------------- fused GEMM + per-group ADC ----------------
// R0 frame (128x128 tile, 256 thr = 4 waves, grid (256,2) = 2 blocks/CU) with:
// (1) slab in lB-clone layout: [204 px][32 ch] @64B stride, word slot rotated by
//     (P>>1)&3 (source-side jsrc pre-swizzle; identical lane->bank structure to the
//     proven 0-conflict B read). 8-ch tail word in sA8 (16B stride). Fixes the
//     measured 8-extra-cycles-per-A-read conflict of the 80B-stride slab.
// (2) T3+T4: B + slab double-buffered; chunk t+1 staged BEFORE computing chunk t;
//     counted s_waitcnt vmcnt(6|11) + raw s_barrier -- loads stay in flight across
//     a full chunk of compute. All waves issue identical load counts per iteration
//     (slab loads masked tid<204 uniformly), so the per-wave vmcnt(N) with
//     N = this-iteration issues exactly drains all older loads.
// LDS: 49152(B x2) + 26112(slab32 x2) + 3264(sA8) + 64 = 78592 B -> 2 blocks/CU.
// dA=4 taps (g=7 r=0; g=8 r<=4, verified exhaustively) read two b64 halves with a
// lane-select on the fq=3 tail into sA8. f64 ADC fold + MFMA order unchanged.
__global__ __launch_bounds__(256, 2) void gemm_adc(const u16* __restrict__ qa,
                                                   const u16* __restrict__ wq,
                                                   const float* __restrict__ pmax,
                                                   float* __restrict__ out) {
  __shared__ __align__(16) u16 lB[24576];     // 2 bufs x 3 runs x 128 rows x 32
  __shared__ __align__(16) u16 sA32[13056];   // 2 bufs x 204 px x 32 ch
  __shared__ __align__(16) u16 sA8[1632];     // 204 px x 8 ch (single buffer)
  __shared__ float sred[16];
  const int tid = threadIdx.x;
  float mx, mw;
  reduce_pmax(pmax, tid, 256, sred, mx, mw);

  const int mblk = blockIdx.x, nblk = blockIdx.y;
  const int b = mblk >> 3;
  const int p0 = (mblk & 7) * 128;        // pixel base (4 image rows of 32)
  const int y0 = (mblk & 7) * 4;          // slab top row in padded coords
  const int n0 = nblk * 128;
  const int lane = tid & 63, wv = tid >> 6;
  const int wm = (wv & 1) * 64, wn = (wv >> 1) * 64;
  const int fm = lane & 15, fq = lane >> 4;
  const int swz = (fq + ((fm >> 1) & 3)) & 3;

  double sa = (double)mx + 1e-12;
  double sw = (double)mw + 1e-12;
  double Sstep = sa * sw * 0.999 / 459.0;   // I/step = intsum * Sstep

  // per-thread slab pixel base for each mi fragment row
  int pixb[4];
#pragma unroll
  for (int mi = 0; mi < 4; mi++) {
    int pr = wm + mi * 16 + fm;
    pixb[mi] = (pr >> 5) * 34 + (pr & 31);
  }

  // B staging geometry (identical to proven kernel)
  const int r0 = tid >> 2;
  const int jsrc = ((tid & 3) - ((tid >> 3) & 3)) & 3;
  const u16* BbH[2];
#pragma unroll
  for (int h = 0; h < 2; h++)
    BbH[h] = wq + (size_t)(n0 + r0 + 64 * h) * KTOT + jsrc * 8;

  const u16* Abase = qa + (size_t)b * QA_BSTRIDE + (size_t)y0 * PADH * NC;

  floatx4 acc[4][4];
  float tot[4][4][4];
#pragma unroll
  for (int mi = 0; mi < 4; mi++)
#pragma unroll
    for (int ni = 0; ni < 4; ni++)
#pragma unroll
      for (int rr = 0; rr < 4; rr++) { acc[mi][ni][rr] = 0.f; tot[mi][ni][rr] = 0.f; }

  // ---- staging lambdas (all waves issue identical load counts) ----
  auto STAGE_B = [&](int gs, int rcs, int bB) {
    int kb0 = gs * GK + rcs * 3 * RUN;
#pragma unroll
    for (int i = 0; i < 6; i++)
      __builtin_amdgcn_global_load_lds(
          (const AS1 void*)(BbH[i & 1] + kb0 + (i >> 1) * RUN),
          (AS3 void*)&lB[bB + (tid + 256 * i) * 8], 16, 0, 0);
  };
  auto STAGE_SLAB = [&](int gp, int aB) {
    int cw = ((256 * gp) / 9) & ~3;
    const u16* src = Abase + cw;
    if (tid < 204) {
#pragma unroll
      for (int i = 0; i < 4; i++) {
        int s = i * 204 + tid;
        int p = s >> 2;
        int js = ((s & 3) - ((s >> 3) & 3)) & 3;
        __builtin_amdgcn_global_load_lds(
            (const AS1 void*)(src + p * NC + js * 8),
            (AS3 void*)&sA32[aB + s * 8], 16, 0, 0);
      }
      __builtin_amdgcn_global_load_lds(
          (const AS1 void*)(src + tid * NC + 32),
          (AS3 void*)&sA8[tid * 8], 16, 0, 0);
    }
  };
  auto FOLD = [&]() {
#pragma unroll
    for (int mi = 0; mi < 4; mi++)
#pragma unroll
      for (int ni = 0; ni < 4; ni++)
#pragma unroll
        for (int rr = 0; rr < 4; rr++) {
          double d = (double)acc[mi][ni][rr] * Sstep;
          float tf = (float)rint(d);
          tf = fminf(fmaxf(tf, -128.f), 127.f);
          tot[mi][ni][rr] += tf;
          acc[mi][ni][rr] = 0.f;
        }
  };

  // ---- prologue: slab(g=0) + B(chunk0) in flight (11 loads) ----
  STAGE_SLAB(0, 0);
  STAGE_B(0, 0, 0);
  int gs = 0, rcs = 1;          // next chunk to stage
  int g = 0, rc = 0, rc3 = 0, rc34 = 0;   // current compute chunk

#pragma unroll 1
  for (int t = 0; t < 27; ++t) {
    const int bb = (t & 1) * 12288;
    const int ab = (g & 1) * 6528;
    // 1) issue next chunk's B
    if (t < 26) {
      STAGE_B(gs, rcs, ((t + 1) & 1) * 12288);
      if (++rcs == 3) { rcs = 0; ++gs; }
    }
    // 2) issue next group's slab on the last chunk of each group
    bool slab_staged = false;
    if (rc == 2 && g < 8) {
      STAGE_SLAB(g + 1, ((g + 1) & 1) * 6528);
      slab_staged = true;
    }
    // 3) fold previous group's ADC while loads fly
    if (rc == 0 && t > 0) FOLD();
    // 4) counted wait: drain everything OLDER than this iteration's issues
    if (t == 26)           asm volatile("s_waitcnt vmcnt(0)" ::: "memory");
    else if (slab_staged)  asm volatile("s_waitcnt vmcnt(11)" ::: "memory");
    else                   asm volatile("s_waitcnt vmcnt(6)" ::: "memory");
    __builtin_amdgcn_s_barrier();
    __builtin_amdgcn_sched_barrier(0);
    // 5) compute chunk t: 3 runs x 16 MFMA per wave
    __builtin_amdgcn_s_setprio(1);
#pragma unroll
    for (int ri = 0; ri < 3; ri++) {
      int r = rc3 + ri;
      bool d4 = (g == 7 && r == 0) || (g == 8 && r <= 4);
      short8 afr[4], bfr[4];
#pragma unroll
      for (int ni = 0; ni < 4; ni++)
        bfr[ni] = *(const short8*)&lB[bb + ri * 4096 + (wn + ni * 16 + fm) * RUN + swz * 8];
      if (!d4) {
#pragma unroll
        for (int mi = 0; mi < 4; mi++) {
          int P = pixb[mi] + rc34 + ri;
          int rot = (P >> 1) & 3;
          afr[mi] = *(const short8*)&sA32[ab + P * 32 + (((fq + rot) & 3) << 3)];
        }
      } else {
#pragma unroll
        for (int mi = 0; mi < 4; mi++) {
          int P = pixb[mi] + rc34 + ri;
          int rot = (P >> 1) & 3;
          union { short8 v8; s4v v4[2]; } u;
          u.v4[0] = *(const s4v*)&sA32[ab + P * 32 + (((fq + rot) & 3) << 3) + 4];
          const u16* hi = (fq < 3) ? &sA32[ab + P * 32 + (((fq + 1 + rot) & 3) << 3)]
                                   : &sA8[P * 8];
          u.v4[1] = *(const s4v*)hi;
          afr[mi] = u.v8;
        }
      }
#pragma unroll
      for (int mi = 0; mi < 4; mi++)
#pragma unroll
        for (int ni = 0; ni < 4; ni++)
          acc[mi][ni] = __builtin_amdgcn_mfma_f32_16x16x32_bf16(afr[mi], bfr[ni], acc[mi][ni], 0, 0, 0);
    }
    __builtin_amdgcn_s_setprio(0);
    __builtin_amdgcn_sched_barrier(0);
    __builtin_amdgcn_s_barrier();
    // 6) advance compute indices
    if (++rc == 3) { rc = 0; ++g; rc3 = 0; rc34 = 0; }
    else { rc3 += 3; rc34 += 34; }
  }
  FOLD();                                       // group 8

  // ---- epilogue ----
#pragma unroll
  for (int mi = 0; mi < 4; mi++)
#pragma unroll
    for (int ni = 0; ni < 4; ni++) {
      int o = n0 + wn + ni * 16 + fm;
      int p = p0 + wm + mi * 16 + (lane >> 4) * 4;
      float4 o4;
      o4.x = tot[mi][ni][0] * 1e-3f;
      o4.y = tot[mi][ni][1] * 1e-3f;
      o4.z = tot[mi][ni][2] * 1e-3f;
      o4.w = tot[mi][ni][3] * 1e-3f;
      *(float4*)(out + ((size_t)(b * NO + o)) * NPIX + p) = o4;
    }
}

extern "C" void kernel_launch(void* const* d_in, const int* in_sizes, int n_in,
                              void* d_out, int out_size, void* d_ws, size_t ws_size,
                              hipStream_t stream) {
  const float* x = (const float*)d_in[0];
  const float* w = (const float*)d_in[1];
  float* out = (float*)d_out;

  float* pmax = (float*)d_ws;                                // 1088 slots
  u16* qa = (u16*)((char*)d_ws + 8192);                      // padded acts: 18,939,904 B
  u16* wq = (u16*)((char*)d_ws + 8192 + 18939904 + 8192);    // weights: 256*2592*2 B

  fused_pre<<<1376, 256, 0, stream>>>((const float4*)x, (NB * NC * NH * NW) / 4,
                                      (const float4*)w, (NO * NC * KPIX) / 4,
                                      pmax, qa);
  fused_quant<<<1024 + 2592, 256, 0, stream>>>(x, w, pmax, qa, wq, out + (out_size - 1));
  gemm_adc<<<dim3(256, 2), 256, 0, stream>>>(qa, wq, pmax, out);
}

// Round 4
// 146.762 us; speedup vs baseline: 1.0667x; 1.0667x over previous
//
#include <hip/hip_runtime.h>
#include <stdint.h>

typedef unsigned short u16;
typedef __attribute__((ext_vector_type(8))) short short8;
typedef __attribute__((ext_vector_type(4))) float floatx4;

#define NB 32
#define NC 256
#define NH 32
#define NW 32
#define NO 256
#define NPIX (NH*NW)     // 1024
#define KPIX 9
#define NG 9             // subarrays (groups)
#define RUN 32           // padded run length (per kernel-tap within group)
#define GK (NG*RUN)      // 288 k-slots per group
#define KTOT (NG*GK)     // 2592 k-slots
#define PADH 34
#define PADSP (PADH*PADH)       // 1156
#define QA_BSTRIDE (PADSP*NC)   // 295936 elems per batch

#define AS1 __attribute__((address_space(1)))
#define AS3 __attribute__((address_space(3)))

// ---------------- fused: per-block absmax slots + zero qa halo borders ----------------
__global__ void fused_pre(const float4* __restrict__ x4, int nx4,
                          const float4* __restrict__ w4, int nw4,
                          float* __restrict__ pmax, u16* __restrict__ qa) {
  int bid = blockIdx.x;
  if (bid >= 1088) {
    int zb = bid - 1088;              // 9 blocks per batch
    int b = zb / 9;
    int rem = (zb % 9) * 256 + threadIdx.x;   // need <2112 (132 px * 16 ch-groups)
    if (rem >= 2112) return;
    int pb = rem >> 4, c16 = rem & 15;
    int y, x;
    if (pb < 68) { y = (pb >= 34) ? 33 : 0; x = pb % 34; }
    else { int q = pb - 68; y = 1 + (q >> 1); x = (q & 1) ? 33 : 0; }
    uint4 z; z.x = z.y = z.z = z.w = 0u;
    *(uint4*)(qa + ((size_t)(b * PADH + y) * PADH + x) * NC + c16 * 16) = z;
    return;
  }
  const float4* p; int n4; int nb, b0;
  if (bid < 1024) { p = x4; n4 = nx4; nb = 1024; b0 = bid; }
  else            { p = w4; n4 = nw4; nb = 64;   b0 = bid - 1024; }
  float m = 0.f;
  for (int i = b0 * blockDim.x + threadIdx.x; i < n4; i += nb * blockDim.x) {
    float4 v = p[i];
    m = fmaxf(m, fmaxf(fmaxf(fabsf(v.x), fabsf(v.y)), fmaxf(fabsf(v.z), fabsf(v.w))));
  }
#pragma unroll
  for (int off = 32; off > 0; off >>= 1)
    m = fmaxf(m, __shfl_down(m, off, 64));
  __shared__ float sm[4];
  int lane = threadIdx.x & 63, wv = threadIdx.x >> 6;
  if (lane == 0) sm[wv] = m;
  __syncthreads();
  if (threadIdx.x == 0)
    pmax[bid] = fmaxf(fmaxf(sm[0], sm[1]), fmaxf(sm[2], sm[3]));
}

// helper: reduce the 1024 x-slots and 64 w-slots
__device__ inline void reduce_pmax(const float* pmax, int tid, int nthreads,
                                   float* sred, float& mx_out, float& mw_out) {
  const float4* pf4 = (const float4*)pmax;
  float mx = 0.f, mw = 0.f;
  for (int t = tid; t < 256; t += nthreads) {
    float4 v = pf4[t];
    mx = fmaxf(mx, fmaxf(fmaxf(v.x, v.y), fmaxf(v.z, v.w)));
  }
  if (tid < 16) {
    float4 v = pf4[256 + tid];
    mw = fmaxf(fmaxf(v.x, v.y), fmaxf(v.z, v.w));
  }
#pragma unroll
  for (int off = 32; off > 0; off >>= 1) {
    mx = fmaxf(mx, __shfl_down(mx, off, 64));
    mw = fmaxf(mw, __shfl_down(mw, off, 64));
  }
  int lane = tid & 63, wv = tid >> 6, nw = nthreads >> 6;
  if (lane == 0) { sred[wv] = mx; sred[8 + wv] = mw; }
  __syncthreads();
  mx = sred[0]; mw = sred[8];
  for (int i = 1; i < nw; i++) { mx = fmaxf(mx, sred[i]); mw = fmaxf(mw, sred[8 + i]); }
  mx_out = mx; mw_out = mw;
}

// ---------------- fused quantization: acts + weights ----------------
// WEIGHT PACKING CHANGE vs prior rounds: slot j of (g,r) run now maps to channel
// cw(g)+j with cw = (256g/9)&~3 UNIFORM across the 9 taps of the group (verified:
// [clo,chi) subset of [cw,cw+32) for all g,r; g=6,7,8 fit exactly). GEMM reads the
// same uniform window, so pairing stays exact; all values are small integers ->
// reordering is bitwise-identical.
__global__ void fused_quant(const float* __restrict__ x, const float* __restrict__ w,
                            const float* __restrict__ pmax,
                            u16* __restrict__ qa, u16* __restrict__ wq,
                            float* __restrict__ lossp) {
  __shared__ float sred[16];
  float mx, mw;
  reduce_pmax(pmax, threadIdx.x, 256, sred, mx, mw);
  int bid = blockIdx.x, tid = threadIdx.x;
  if (bid < 1024) {
    __shared__ u16 ts[32][264];        // [x][c], row stride 264 (16B-aligned rows)
    double s = (double)mx + 1e-12;
    double inv = 255.0 / s;
    int b = bid >> 5, y = bid & 31;
    const float4* x4 = (const float4*)x;
    int xc = tid & 7, crow = tid >> 3;
#pragma unroll
    for (int it = 0; it < 8; it++) {
      int c = crow + 32 * it;
      float4 v = x4[((size_t)(b * NC + c) * NH + y) * 8 + xc];
      float q0 = (float)rint((double)v.x * inv);
      float q1 = (float)rint((double)v.y * inv);
      float q2 = (float)rint((double)v.z * inv);
      float q3 = (float)rint((double)v.w * inv);
      ts[xc * 4 + 0][c] = (u16)(__float_as_uint(q0) >> 16);
      ts[xc * 4 + 1][c] = (u16)(__float_as_uint(q1) >> 16);
      ts[xc * 4 + 2][c] = (u16)(__float_as_uint(q2) >> 16);
      ts[xc * 4 + 3][c] = (u16)(__float_as_uint(q3) >> 16);
    }
    __syncthreads();
    int xx = tid >> 3, qwl = tid & 7;
    u16* orow = qa + ((size_t)(b * PADH + y + 1) * PADH + (xx + 1)) * NC;
#pragma unroll
    for (int it = 0; it < 4; it++) {
      int qw = qwl + 8 * it;
      *(uint4*)(orow + qw * 8) = *(const uint4*)&ts[xx][qw * 8];
    }
    return;
  }
  // ---- weights: 2592 blocks cover NO*KTOT = 663552 slots exactly ----
  double s = (double)mw + 1e-12;
  double inv = 15.0 / s;
  int idx = (bid - 1024) * 256 + tid;
  if (idx == 0) *lossp = 0.0f;                  // a_loss output
  int o = idx / KTOT, kk = idx % KTOT;
  int g = kk / GK, rem = kk % GK;
  int r = rem / RUN, j = rem % RUN;
  int clo = (256 * g - r + 8) / 9;
  int chi = (256 * (g + 1) - r + 8) / 9; if (chi > NC) chi = NC;
  int cst = ((256 * g) / 9) & ~3;               // UNIFORM per-group window start
  int c = cst + j;
  float val = 0.f;
  if (c >= clo && c < chi) {
    float wv = w[((size_t)o * NC + c) * KPIX + r];
    val = (float)rint((double)wv * inv);
  }
  wq[idx] = (u16)(__float_as_uint(val) >> 16);
}

// ---------------- fused GEMM + per-group ADC ----------------
// Proven R0/R2 drain frame: 128x128 tile, 256 thr (4 waves x 64x64), grid (256,2) =
// 512 blocks = 2/CU, __syncthreads per chunk, no pipeline asm. A is a per-group
// 204px x 32ch slab (13 KB, 4 linear async loads, masked tid<204) in the PROVEN
// conflict-free rotated layout (stride 32 u16, word slot = (fq + (P>>1)&3)&3,
// store-side pre-swizzle). Uniform per-group channel window (cw) kills the d4
// split-read path entirely. All 36 rotated A-fragment addresses are precomputed
// lane-constants (rc unrolled -> static indexing): A-read = 1 ds_read_b128, zero
// per-read VALU. f64 ADC fold overlaps next group's staging. B path unchanged.
__global__ __launch_bounds__(256, 2) void gemm_adc(const u16* __restrict__ qa,
                                                   const u16* __restrict__ wq,
                                                   const float* __restrict__ pmax,
                                                   float* __restrict__ out) {
  __shared__ __align__(16) u16 lB[12288];     // 24576 B: 3 runs x 128 rows x 32
  __shared__ __align__(16) u16 sA[6528];      // 13056 B: 204 px x 32 ch (rotated)
  __shared__ float sred[16];
  const int tid = threadIdx.x;
  float mx, mw;
  reduce_pmax(pmax, tid, 256, sred, mx, mw);

  const int mblk = blockIdx.x, nblk = blockIdx.y;
  const int b = mblk >> 3;
  const int p0 = (mblk & 7) * 128;        // pixel base (4 image rows of 32)
  const int y0 = (mblk & 7) * 4;          // slab top row in padded coords
  const int n0 = nblk * 128;
  const int lane = tid & 63, wv = tid >> 6;
  const int wm = (wv & 1) * 64, wn = (wv >> 1) * 64;
  const int fm = lane & 15, fq = lane >> 4;
  const int swz = (fq + ((fm >> 1) & 3)) & 3;

  double sa = (double)mx + 1e-12;
  double sw = (double)mw + 1e-12;
  double Sstep = sa * sw * 0.999 / 459.0;   // I/step = intsum * Sstep

  // ---- precompute all 36 A-fragment LDS addresses (u16 units), lane-constant ----
  const int OFS[9] = {0, 1, 2, 34, 35, 36, 68, 69, 70};   // rc*34 + ri
  int addrA[4][9];
#pragma unroll
  for (int mi = 0; mi < 4; mi++) {
    int pr = wm + mi * 16 + fm;
    int pixb = (pr >> 5) * 34 + (pr & 31);
#pragma unroll
    for (int t = 0; t < 9; t++) {
      int P = pixb + OFS[t];
      addrA[mi][t] = P * 32 + (((fq + ((P >> 1) & 3)) & 3) << 3);
    }
  }
  // B read offsets (lane-constant)
  int bno[4];
#pragma unroll
  for (int ni = 0; ni < 4; ni++) bno[ni] = (wn + ni * 16 + fm) * RUN + swz * 8;

  // B staging geometry (identical to proven kernel)
  const int r0 = tid >> 2;
  const int jsrc = ((tid & 3) - ((tid >> 3) & 3)) & 3;
  const u16* BbH[2];
#pragma unroll
  for (int h = 0; h < 2; h++)
    BbH[h] = wq + (size_t)(n0 + r0 + 64 * h) * KTOT + jsrc * 8;

  // slab staging geometry: 816 slots (204 px x 4 words), store-side rotation
  const u16* Abase = qa + (size_t)b * QA_BSTRIDE + (size_t)y0 * PADH * NC;
  const bool sact = tid < 204;
  int soff[4], sdst[4];
#pragma unroll
  for (int i = 0; i < 4; i++) {
    int s = i * 204 + tid;
    soff[i] = (s >> 2) * NC + ((((s & 3) - ((s >> 3) & 3)) & 3) << 3);
    sdst[i] = s * 8;
  }

  floatx4 acc[4][4];
  float tot[4][4][4];
#pragma unroll
  for (int mi = 0; mi < 4; mi++)
#pragma unroll
    for (int ni = 0; ni < 4; ni++)
#pragma unroll
      for (int rr = 0; rr < 4; rr++) { acc[mi][ni][rr] = 0.f; tot[mi][ni][rr] = 0.f; }

#pragma unroll 1
  for (int g = 0; g < NG; g++) {
    int cw = ((256 * g) / 9) & ~3;     // uniform per-group channel window
    // stage slab(g) + B(g, rc=0); previous group's last reads completed before the
    // trailing __syncthreads of its rc=2 chunk, so single-buffering is safe.
    if (sact) {
      const u16* srcg = Abase + cw;
#pragma unroll
      for (int i = 0; i < 4; i++)
        __builtin_amdgcn_global_load_lds((const AS1 void*)(srcg + soff[i]),
                                         (AS3 void*)&sA[sdst[i]], 16, 0, 0);
    }
    {
      int kb0 = g * GK;
#pragma unroll
      for (int i = 0; i < 6; i++)
        __builtin_amdgcn_global_load_lds((const AS1 void*)(BbH[i & 1] + kb0 + (i >> 1) * RUN),
                                         (AS3 void*)&lB[(tid + 256 * i) * 8], 16, 0, 0);
    }
    // fold previous group's ADC (registers only) while the loads fly
    if (g > 0) {
#pragma unroll
      for (int mi = 0; mi < 4; mi++)
#pragma unroll
        for (int ni = 0; ni < 4; ni++)
#pragma unroll
          for (int rr = 0; rr < 4; rr++) {
            double d = (double)acc[mi][ni][rr] * Sstep;
            float tf = (float)rint(d);
            tf = fminf(fmaxf(tf, -128.f), 127.f);
            tot[mi][ni][rr] += tf;
            acc[mi][ni][rr] = 0.f;
          }
    }
#pragma unroll
    for (int rc = 0; rc < 3; rc++) {
      __syncthreads();               // staged chunk landed (syncthreads drains vmcnt)
      // ---- 3 runs x 16 MFMA per wave ----
#pragma unroll
      for (int ri = 0; ri < 3; ri++) {
        short8 afr[4], bfr[4];
#pragma unroll
        for (int mi = 0; mi < 4; mi++)
          afr[mi] = *(const short8*)&sA[addrA[mi][rc * 3 + ri]];
#pragma unroll
        for (int ni = 0; ni < 4; ni++)
          bfr[ni] = *(const short8*)&lB[ri * 4096 + bno[ni]];
#pragma unroll
        for (int mi = 0; mi < 4; mi++)
#pragma unroll
          for (int ni = 0; ni < 4; ni++)
            acc[mi][ni] = __builtin_amdgcn_mfma_f32_16x16x32_bf16(afr[mi], bfr[ni], acc[mi][ni], 0, 0, 0);
      }
      __syncthreads();               // reads done before overwrite
      if (rc < 2) {                  // stage next chunk's B
        int kb0 = g * GK + (rc + 1) * 3 * RUN;
#pragma unroll
        for (int i = 0; i < 6; i++)
          __builtin_amdgcn_global_load_lds((const AS1 void*)(BbH[i & 1] + kb0 + (i >> 1) * RUN),
                                           (AS3 void*)&lB[(tid + 256 * i) * 8], 16, 0, 0);
      }
    }
  }
  // ---- final group's ADC fold ----
#pragma unroll
  for (int mi = 0; mi < 4; mi++)
#pragma unroll
    for (int ni = 0; ni < 4; ni++)
#pragma unroll
      for (int rr = 0; rr < 4; rr++) {
        double d = (double)acc[mi][ni][rr] * Sstep;
        float tf = (float)rint(d);
        tf = fminf(fmaxf(tf, -128.f), 127.f);
        tot[mi][ni][rr] += tf;
      }

  // ---- epilogue ----
#pragma unroll
  for (int mi = 0; mi < 4; mi++)
#pragma unroll
    for (int ni = 0; ni < 4; ni++) {
      int o = n0 + wn + ni * 16 + fm;
      int p = p0 + wm + mi * 16 + fq * 4;
      float4 o4;
      o4.x = tot[mi][ni][0] * 1e-3f;
      o4.y = tot[mi][ni][1] * 1e-3f;
      o4.z = tot[mi][ni][2] * 1e-3f;
      o4.w = tot[mi][ni][3] * 1e-3f;
      *(float4*)(out + ((size_t)(b * NO + o)) * NPIX + p) = o4;
    }
}

extern "C" void kernel_launch(void* const* d_in, const int* in_sizes, int n_in,
                              void* d_out, int out_size, void* d_ws, size_t ws_size,
                              hipStream_t stream) {
  const float* x = (const float*)d_in[0];
  const float* w = (const float*)d_in[1];
  float* out = (float*)d_out;

  float* pmax = (float*)d_ws;                                // 1088 slots
  u16* qa = (u16*)((char*)d_ws + 8192);                      // padded acts: 18,939,904 B
  u16* wq = (u16*)((char*)d_ws + 8192 + 18939904 + 8192);    // weights: 256*2592*2 B

  fused_pre<<<1376, 256, 0, stream>>>((const float4*)x, (NB * NC * NH * NW) / 4,
                                      (const float4*)w, (NO * NC * KPIX) / 4,
                                      pmax, qa);
  fused_quant<<<1024 + 2592, 256, 0, stream>>>(x, w, pmax, qa, wq, out + (out_size - 1));
  gemm_adc<<<dim3(256, 2), 256, 0, stream>>>(qa, wq, pmax, out);
}